// Round 6
// baseline (663.897 us; speedup 1.0000x reference)
//
#include <hip/hip_runtime.h>
#include <hip/hip_bf16.h>

#define Bq 8
#define Nq 1024
#define Dq 768
#define Hq 12
#define Zq 64
#define HIDq 3072
#define BN (Bq*Nq)            // 8192
#define QKP 1536              // pitch of fused QK / AV12 buffers

typedef unsigned short u16;
typedef short s16x8 __attribute__((ext_vector_type(8)));
typedef float f32x4 __attribute__((ext_vector_type(4)));
typedef float f32x16 __attribute__((ext_vector_type(16)));
typedef unsigned short u16x4 __attribute__((ext_vector_type(4)));

#define MFMA16 __builtin_amdgcn_mfma_f32_16x16x32_bf16
#define MFMA32 __builtin_amdgcn_mfma_f32_32x32x16_bf16
#define GLOAD16(g, l) __builtin_amdgcn_global_load_lds( \
    (const __attribute__((address_space(1))) void*)(const void*)(g), \
    (__attribute__((address_space(3))) void*)(l), 16, 0, 0)

__device__ __forceinline__ u16 f2bf(float f) {
  unsigned u = __float_as_uint(f);
  return (u16)((u + 0x7FFFu + ((u >> 16) & 1u)) >> 16);
}

// XCD-aware swizzle: all gx tiles of a row-panel (and gy/8 consecutive panels)
// land on one XCD (dispatch round-robins linear id % 8). Requires gy % 8 == 0.
__device__ __forceinline__ void xcd_swizzle(int gx, int gy, int& bx, int& by) {
  int l = blockIdx.y * gx + blockIdx.x;
  int c = l & 7, j = l >> 3;
  by = c * (gy >> 3) + j / gx;
  bx = j % gx;
}

// ---------------------------------------------------------------------------
// f32 -> bf16 convert (n % 4 == 0)
// ---------------------------------------------------------------------------
__global__ __launch_bounds__(256) void cvt_bf16(const float* __restrict__ in,
                                                u16* __restrict__ out, int n) {
  int i = (blockIdx.x * 256 + threadIdx.x) * 4;
  if (i >= n) return;
  float4 v = *(const float4*)&in[i];
  u16x4 o; o[0] = f2bf(v.x); o[1] = f2bf(v.y); o[2] = f2bf(v.z); o[3] = f2bf(v.w);
  *(u16x4*)&out[i] = o;
}

// ---------------------------------------------------------------------------
// f32 [R][C] -> bf16 [R][C] (pitch out_p) AND bf16 transposed [C][R] (pitch outT_p)
// grid (C/64, R/64)
// ---------------------------------------------------------------------------
__global__ __launch_bounds__(256) void cvt_tr(const float* __restrict__ in,
                                              u16* __restrict__ out, u16* __restrict__ outT,
                                              int C, int out_p, int outT_p) {
  __shared__ u16 T[64][72];
  const int t = threadIdx.x;
  const int r0 = blockIdx.y * 64, c0 = blockIdx.x * 64;
  const int r = t >> 3, c8 = (t & 7) * 8;
#pragma unroll
  for (int p = 0; p < 2; p++) {
    const float* ip = &in[(size_t)(r0 + r + p * 32) * C + c0 + c8];
    float4 v0 = *(const float4*)ip, v1 = *(const float4*)(ip + 4);
    u16 tmp[8] = {f2bf(v0.x), f2bf(v0.y), f2bf(v0.z), f2bf(v0.w),
                  f2bf(v1.x), f2bf(v1.y), f2bf(v1.z), f2bf(v1.w)};
    *(uint4*)&out[(size_t)(r0 + r + p * 32) * out_p + c0 + c8] = *(uint4*)tmp;
    *(uint4*)&T[r + p * 32][c8] = *(uint4*)tmp;
  }
  __syncthreads();
#pragma unroll
  for (int p = 0; p < 2; p++) {
    int oc = r + p * 32;
    u16 tmp[8];
#pragma unroll
    for (int j = 0; j < 8; j++) tmp[j] = T[c8 + j][oc];
    *(uint4*)&outT[(size_t)(c0 + oc) * outT_p + r0 + c8] = *(uint4*)tmp;
  }
}

// ---------------------------------------------------------------------------
// Batched 64x64-tiled bf16 transpose. base = ptr + (z/inner)*bs_o + (z%inner)*bs_i
// ---------------------------------------------------------------------------
__global__ __launch_bounds__(256) void transpose_bf16(
    const u16* __restrict__ in, u16* __restrict__ out,
    int in_pitch, int out_pitch, int inner_n,
    long in_bs_o, long in_bs_i, long out_bs_o, long out_bs_i) {
  __shared__ u16 T[64][72];
  const int t = threadIdx.x;
  const int bz = blockIdx.z;
  const long iboff = (long)(bz / inner_n) * in_bs_o + (long)(bz % inner_n) * in_bs_i;
  const long oboff = (long)(bz / inner_n) * out_bs_o + (long)(bz % inner_n) * out_bs_i;
  const u16* ip = in + iboff + (long)(blockIdx.y * 64) * in_pitch + blockIdx.x * 64;
  u16* op = out + oboff + (long)(blockIdx.x * 64) * out_pitch + blockIdx.y * 64;
  const int r = t >> 3, c8 = (t & 7) * 8;
#pragma unroll
  for (int p = 0; p < 2; p++)
    *(uint4*)&T[r + p * 32][c8] = *(const uint4*)(ip + (size_t)(r + p * 32) * in_pitch + c8);
  __syncthreads();
#pragma unroll
  for (int p = 0; p < 2; p++) {
    int oc = r + p * 32;
    u16 tmp[8];
#pragma unroll
    for (int j = 0; j < 8; j++) tmp[j] = T[c8 + j][oc];
    *(uint4*)(op + (size_t)oc * out_pitch + c8) = *(uint4*)tmp;
  }
}

// ---------------------------------------------------------------------------
// Single-wave GEMM: 64-thread blocks, 64x64 tile, 32x32x16 MFMA, 2x2 outer.
// C[M,N] = A[M,K] @ B[N,K]^T (+ optional second source pair when DUAL).
// LDS staged in fragment-linear 1KB chunks: chunk(ks,m) holds rows m*32..+31,
// k ks*16..+15; lane reads its b128 at chunkbase + lane*16 (conflict-free).
// grid (N/64, M/64), XCD-swizzled. No s_barrier (single-wave WG).
// ---------------------------------------------------------------------------
template<bool RELU, bool DUAL, bool OUTF32>
__global__ __launch_bounds__(64, 4) void gemm_w64(
    const u16* __restrict__ A0, const u16* __restrict__ B0, int pitch0, int K0,
    const u16* __restrict__ A1, const u16* __restrict__ B1, int pitch1, int K1,
    void* __restrict__ Cv, int N) {
  __shared__ u16 As[2048];   // 4KB: 4 chunks of 1KB
  __shared__ u16 Bs[2048];
  int bx, by;
  xcd_swizzle(gridDim.x, gridDim.y, bx, by);
  const int l = threadIdx.x;
  const int ln = l & 31, kh = l >> 5;
  const int bm = by * 64, bn = bx * 64;

  f32x16 acc[2][2];
#pragma unroll
  for (int i = 0; i < 2; i++)
#pragma unroll
    for (int j = 0; j < 2; j++)
#pragma unroll
      for (int r = 0; r < 16; r++) acc[i][j][r] = 0.f;

  const int nsrc = DUAL ? 2 : 1;
  for (int s = 0; s < nsrc; s++) {
    const u16* A = s ? A1 : A0;
    const u16* B = s ? B1 : B0;
    const int pitch = s ? pitch1 : pitch0;
    const int Kend = s ? K1 : K0;
    for (int k0 = 0; k0 < Kend; k0 += 32) {
#pragma unroll
      for (int ks = 0; ks < 2; ks++)
#pragma unroll
        for (int m = 0; m < 2; m++) {
          const int ch = (ks * 2 + m) * 512;
          GLOAD16(A + (size_t)(bm + m * 32 + ln) * pitch + k0 + ks * 16 + kh * 8,
                  As + ch + l * 8);
          GLOAD16(B + (size_t)(bn + m * 32 + ln) * pitch + k0 + ks * 16 + kh * 8,
                  Bs + ch + l * 8);
        }
      __syncthreads();
#pragma unroll
      for (int ks = 0; ks < 2; ks++) {
        s16x8 a0 = *(const s16x8*)&As[(ks * 2 + 0) * 512 + l * 8];
        s16x8 a1 = *(const s16x8*)&As[(ks * 2 + 1) * 512 + l * 8];
        s16x8 b0 = *(const s16x8*)&Bs[(ks * 2 + 0) * 512 + l * 8];
        s16x8 b1 = *(const s16x8*)&Bs[(ks * 2 + 1) * 512 + l * 8];
        acc[0][0] = MFMA32(a0, b0, acc[0][0], 0, 0, 0);
        acc[0][1] = MFMA32(a0, b1, acc[0][1], 0, 0, 0);
        acc[1][0] = MFMA32(a1, b0, acc[1][0], 0, 0, 0);
        acc[1][1] = MFMA32(a1, b1, acc[1][1], 0, 0, 0);
      }
      __syncthreads();
    }
  }
  // C/D layout (32x32): col = ln, row = (r&3) + 8*(r>>2) + 4*kh
#pragma unroll
  for (int mt = 0; mt < 2; mt++)
#pragma unroll
    for (int nt = 0; nt < 2; nt++)
#pragma unroll
      for (int r = 0; r < 16; r++) {
        int row = bm + mt * 32 + (r & 3) + 8 * (r >> 2) + 4 * kh;
        int col = bn + nt * 32 + ln;
        float v = acc[mt][nt][r];
        if (RELU) v = fmaxf(v, 0.f);
        if (OUTF32) ((float*)Cv)[(size_t)row * N + col] = v;
        else        ((u16*)Cv)[(size_t)row * N + col] = f2bf(v);
      }
}

// ---------------------------------------------------------------------------
// Attention pass 1 (no max pass; scores are O(1), exp-safe): per (b,h,64-q).
// P = exp(beta*S), l = sum_k, AV1 = (P/l) @ K via MFMA. Writes AV12[:,0:768], l.
// Q B-fragments hoisted (kt-invariant). XCD-swizzled: 12 bh-panels per XCD.
// ---------------------------------------------------------------------------
__global__ __launch_bounds__(256) void attn_pass1(
    const u16* __restrict__ QKb, const u16* __restrict__ KbT,
    const float* __restrict__ betas, u16* __restrict__ AV12,
    float* __restrict__ lg) {
  __shared__ u16 Qs[2][64][32];
  __shared__ u16 Ks[2][64][32];
  __shared__ u16 Kts[2][64][32];
  __shared__ u16 Ps[64][72];
  __shared__ float red[4][64];
  __shared__ float li[64];

  const int t = threadIdx.x, l = t & 63, w = t >> 6;
  const int lq = l & 15, quad = l >> 4;
  const int c = blockIdx.x & 7, j = blockIdx.x >> 3;
  const int bh = c * 12 + j / 16, qt = j % 16;
  const int b = bh / Hq, h = bh % Hq;
  const int q0 = qt * 64;
  const float beta = betas[h];
  const u16* Qh = QKb + (size_t)(b * Nq) * QKP + h * 64;
  const u16* Kh = Qh + Dq;
  const u16* KTh = KbT + (size_t)bh * 64 * Nq;
  u16* QsF = &Qs[0][0][0]; u16* KsF = &Ks[0][0][0]; u16* KtsF = &Kts[0][0][0];

#pragma unroll
  for (int p = 0; p < 2; p++) {
    int idx = p * 256 + t;
    GLOAD16(Qh + (size_t)(q0 + ((idx >> 2) & 63)) * QKP + (idx >> 8) * 32 + (idx & 3) * 8,
            QsF + idx * 8);
  }
  __syncthreads();
  s16x8 bqf[2][4];
#pragma unroll
  for (int zs = 0; zs < 2; zs++)
#pragma unroll
    for (int nt = 0; nt < 4; nt++)
      bqf[zs][nt] = *(const s16x8*)&Qs[zs][nt * 16 + lq][quad * 8];

  float lsum[4] = {0.f, 0.f, 0.f, 0.f};
  f32x4 ao[4];
#pragma unroll
  for (int nt = 0; nt < 4; nt++) ao[nt] = (f32x4){0.f, 0.f, 0.f, 0.f};

  for (int kt = 0; kt < 16; kt++) {
#pragma unroll
    for (int p = 0; p < 2; p++) {
      int idx = p * 256 + t;
      GLOAD16(Kh + (size_t)(kt * 64 + ((idx >> 2) & 63)) * QKP + (idx >> 8) * 32 + (idx & 3) * 8,
              KsF + idx * 8);
      GLOAD16(KTh + (size_t)((idx >> 2) & 63) * Nq + kt * 64 + (idx >> 8) * 32 + (idx & 3) * 8,
              KtsF + idx * 8);
    }
    __syncthreads();
    // S^T tile: col q = nt*16+lq, row k = kt*64 + w*16 + quad*4 + r
    f32x4 sc[4];
#pragma unroll
    for (int nt = 0; nt < 4; nt++) sc[nt] = (f32x4){0.f, 0.f, 0.f, 0.f};
#pragma unroll
    for (int zs = 0; zs < 2; zs++) {
      s16x8 a = *(const s16x8*)&Ks[zs][w * 16 + lq][quad * 8];
#pragma unroll
      for (int nt = 0; nt < 4; nt++)
        sc[nt] = MFMA16(a, bqf[zs][nt], sc[nt], 0, 0, 0);
    }
#pragma unroll
    for (int nt = 0; nt < 4; nt++) {
      u16x4 pk;
#pragma unroll
      for (int r = 0; r < 4; r++) {
        float e = __expf(sc[nt][r] * beta);
        lsum[nt] += e;
        pk[r] = f2bf(e);
      }
      *(u16x4*)&Ps[nt * 16 + lq][w * 16 + quad * 4] = pk;
    }
    __syncthreads();
    // O[q][z] += P[q][k] * K[k][z]; B-frag reads Kt rows (z-major)
#pragma unroll
    for (int ks = 0; ks < 2; ks++) {
      s16x8 a = *(const s16x8*)&Ps[w * 16 + lq][ks * 32 + quad * 8];
#pragma unroll
      for (int nt = 0; nt < 4; nt++) {
        s16x8 bk = *(const s16x8*)&Kts[ks][nt * 16 + lq][quad * 8];
        ao[nt] = MFMA16(a, bk, ao[nt], 0, 0, 0);
      }
    }
    __syncthreads();
  }
#pragma unroll
  for (int nt = 0; nt < 4; nt++) {
    float v = lsum[nt];
    v += __shfl_xor(v, 16, 64);
    v += __shfl_xor(v, 32, 64);
    if (l < 16) red[w][nt * 16 + lq] = v;
  }
  __syncthreads();
  if (t < 64) {
    float s = red[0][t] + red[1][t] + red[2][t] + red[3][t];
    lg[(size_t)bh * Nq + q0 + t] = s;
    li[t] = 1.0f / s;
  }
  __syncthreads();
  u16* Oh = AV12 + (size_t)(b * Nq + q0) * QKP + h * 64;
  float lr[4];
#pragma unroll
  for (int r = 0; r < 4; r++) lr[r] = li[w * 16 + quad * 4 + r];
#pragma unroll
  for (int nt = 0; nt < 4; nt++)
#pragma unroll
    for (int r = 0; r < 4; r++)
      Oh[(size_t)(w * 16 + quad * 4 + r) * QKP + nt * 16 + lq] = f2bf(ao[nt][r] * lr[r]);
}

// ---------------------------------------------------------------------------
// Attention pass 2: per (b,h,64-k). Recompute P from l (m=0), accumulate
// AV2[k,z] = sum_q P[q,k] Q[q,z]. K B-fragments hoisted. XCD-swizzled.
// ---------------------------------------------------------------------------
__global__ __launch_bounds__(256) void attn_pass2(
    const u16* __restrict__ QKb, const u16* __restrict__ QbT,
    const float* __restrict__ betas, u16* __restrict__ AV12,
    const float* __restrict__ lg) {
  __shared__ u16 Qs[2][64][32];
  __shared__ u16 Qts[2][64][32];
  __shared__ u16 Ks[2][64][32];
  __shared__ u16 Pts[64][72];
  __shared__ float li_s[64];

  const int t = threadIdx.x, l = t & 63, w = t >> 6;
  const int lq = l & 15, quad = l >> 4;
  const int c = blockIdx.x & 7, j = blockIdx.x >> 3;
  const int bh = c * 12 + j / 16, kt = j % 16;
  const int b = bh / Hq, h = bh % Hq;
  const int k0 = kt * 64;
  const float beta = betas[h];
  const u16* Qh = QKb + (size_t)(b * Nq) * QKP + h * 64;
  const u16* Kh = Qh + Dq;
  const u16* QTh = QbT + (size_t)bh * 64 * Nq;
  u16* QsF = &Qs[0][0][0]; u16* QtsF = &Qts[0][0][0]; u16* KsF = &Ks[0][0][0];

#pragma unroll
  for (int p = 0; p < 2; p++) {
    int idx = p * 256 + t;
    GLOAD16(Kh + (size_t)(k0 + ((idx >> 2) & 63)) * QKP + (idx >> 8) * 32 + (idx & 3) * 8,
            KsF + idx * 8);
  }
  __syncthreads();
  s16x8 bkf[2][4];
#pragma unroll
  for (int zs = 0; zs < 2; zs++)
#pragma unroll
    for (int nt = 0; nt < 4; nt++)
      bkf[zs][nt] = *(const s16x8*)&Ks[zs][nt * 16 + lq][quad * 8];

  f32x4 ao[4];
#pragma unroll
  for (int nt = 0; nt < 4; nt++) ao[nt] = (f32x4){0.f, 0.f, 0.f, 0.f};

  for (int qt = 0; qt < 16; qt++) {
#pragma unroll
    for (int p = 0; p < 2; p++) {
      int idx = p * 256 + t;
      GLOAD16(Qh + (size_t)(qt * 64 + ((idx >> 2) & 63)) * QKP + (idx >> 8) * 32 + (idx & 3) * 8,
              QsF + idx * 8);
      GLOAD16(QTh + (size_t)((idx >> 2) & 63) * Nq + qt * 64 + (idx >> 8) * 32 + (idx & 3) * 8,
              QtsF + idx * 8);
    }
    if (t < 64) li_s[t] = 1.0f / lg[(size_t)bh * Nq + qt * 64 + t];
    __syncthreads();
    f32x4 sc[4];
#pragma unroll
    for (int nt = 0; nt < 4; nt++) sc[nt] = (f32x4){0.f, 0.f, 0.f, 0.f};
#pragma unroll
    for (int zs = 0; zs < 2; zs++) {
      s16x8 a = *(const s16x8*)&Qs[zs][w * 16 + lq][quad * 8];
#pragma unroll
      for (int nt = 0; nt < 4; nt++)
        sc[nt] = MFMA16(a, bkf[zs][nt], sc[nt], 0, 0, 0);
    }
    float lr[4];
#pragma unroll
    for (int r = 0; r < 4; r++) lr[r] = li_s[w * 16 + quad * 4 + r];
#pragma unroll
    for (int nt = 0; nt < 4; nt++) {
      u16x4 pk;
#pragma unroll
      for (int r = 0; r < 4; r++)
        pk[r] = f2bf(__expf(sc[nt][r] * beta) * lr[r]);
      *(u16x4*)&Pts[nt * 16 + lq][w * 16 + quad * 4] = pk;
    }
    __syncthreads();
#pragma unroll
    for (int qs = 0; qs < 2; qs++) {
      s16x8 a = *(const s16x8*)&Pts[w * 16 + lq][qs * 32 + quad * 8];
#pragma unroll
      for (int nt = 0; nt < 4; nt++) {
        s16x8 bq = *(const s16x8*)&Qts[qs][nt * 16 + lq][quad * 8];
        ao[nt] = MFMA16(a, bq, ao[nt], 0, 0, 0);
      }
    }
    __syncthreads();
  }
  u16* Oh = AV12 + (size_t)(b * Nq + k0) * QKP + Dq + h * 64;
#pragma unroll
  for (int nt = 0; nt < 4; nt++)
#pragma unroll
    for (int r = 0; r < 4; r++)
      Oh[(size_t)(w * 16 + quad * 4 + r) * QKP + nt * 16 + lq] = f2bf(ao[nt][r]);
}

// ---------------------------------------------------------------------------
extern "C" void kernel_launch(void* const* d_in, const int* in_sizes, int n_in,
                              void* d_out, int out_size, void* d_ws, size_t ws_size,
                              hipStream_t stream) {
  const float* x     = (const float*)d_in[0];
  const float* Wq    = (const float*)d_in[1];
  const float* Wk    = (const float*)d_in[2];
  const float* betas = (const float*)d_in[3];
  const float* Wm    = (const float*)d_in[4];
  float* out = (float*)d_out;

  // workspace layout (u16 units); ~93.4 MiB
  u16* xb   = (u16*)d_ws;                      // 6,291,456
  u16* Wqkb = xb + (size_t)BN * Dq;            // 1,179,648  [1536][768]
  u16* Wmb  = Wqkb + (size_t)QKP * Dq;         // 2,359,296  [3072][768]
  u16* WqkT = Wmb + (size_t)HIDq * Dq;         // 1,179,648  [768][1536]
  u16* QKb  = WqkT + (size_t)Dq * QKP;         // 12,582,912 [8192][1536]
  u16* QbT  = QKb + (size_t)BN * QKP;          // 6,291,456  [96][64][1024]
  u16* KbT  = QbT + (size_t)Bq * Hq * Zq * Nq; // 6,291,456
  u16* AV12 = KbT + (size_t)Bq * Hq * Zq * Nq; // 12,582,912 [8192][1536]
  float* lg = (float*)(AV12 + (size_t)BN * QKP);
  u16* hidb = QKb;   // overlays QKb/QbT/KbT (dead after attention)
  u16* WmT  = xb;    // overlays xb (dead after MLP1), [768][3072]

  dim3 blk(256);
  cvt_bf16<<<(BN * Dq) / 1024, blk, 0, stream>>>(x, xb, BN * Dq);
  cvt_tr<<<dim3(12, 12), blk, 0, stream>>>(Wq, Wqkb, WqkT, Dq, Dq, QKP);
  cvt_tr<<<dim3(12, 12), blk, 0, stream>>>(Wk, Wqkb + (size_t)Dq * Dq, WqkT + Dq, Dq, Dq, QKP);
  cvt_bf16<<<(HIDq * Dq) / 1024, blk, 0, stream>>>(Wm, Wmb, HIDq * Dq);

  // QK = x @ [Wq;Wk]^T  -> bf16 [8192][1536]  (3072 single-wave blocks)
  gemm_w64<false, false, false><<<dim3(QKP / 64, BN / 64), dim3(64), 0, stream>>>(
      xb, Wqkb, Dq, Dq, nullptr, nullptr, 0, 0, QKb, QKP);

  // per-head transposes of Q and K
  transpose_bf16<<<dim3(1, 16, 96), blk, 0, stream>>>(QKb, QbT, QKP, Nq, Hq,
      (long)Nq * QKP, 64, (long)Hq * 64 * Nq, (long)64 * Nq);
  transpose_bf16<<<dim3(1, 16, 96), blk, 0, stream>>>(QKb + Dq, KbT, QKP, Nq, Hq,
      (long)Nq * QKP, 64, (long)Hq * 64 * Nq, (long)64 * Nq);

  // attention
  attn_pass1<<<Bq * Hq * 16, blk, 0, stream>>>(QKb, KbT, betas, AV12, lg);
  attn_pass2<<<Bq * Hq * 16, blk, 0, stream>>>(QKb, QbT, betas, AV12, lg);

  // MLP up-proj: hid = relu(x @ Wm^T) bf16 (6144 single-wave blocks)
  gemm_w64<true, false, false><<<dim3(HIDq / 64, BN / 64), dim3(64), 0, stream>>>(
      xb, Wmb, Dq, Dq, nullptr, nullptr, 0, 0, hidb, HIDq);

  // Wm transpose into xb region (xb dead after MLP1)
  transpose_bf16<<<dim3(12, 48, 1), blk, 0, stream>>>(Wmb, WmT, Dq, HIDq, 1, 0, 0, 0, 0);

  // out = AV12 @ WqkT^T + hid @ WmT^T, f32, single dispatch (1536 blocks)
  gemm_w64<false, true, true><<<dim3(Dq / 64, BN / 64), dim3(64), 0, stream>>>(
      AV12, WqkT, QKP, QKP, hidb, WmT, HIDq, HIDq, out, Dq);
}

// Round 7
// 585.608 us; speedup vs baseline: 1.1337x; 1.1337x over previous
//
#include <hip/hip_runtime.h>
#include <hip/hip_bf16.h>

#define Bq 8
#define Nq 1024
#define Dq 768
#define Hq 12
#define Zq 64
#define HIDq 3072
#define BN (Bq*Nq)            // 8192
#define QKP 1536              // pitch of fused QK / AV12 buffers

typedef unsigned short u16;
typedef short s16x8 __attribute__((ext_vector_type(8)));
typedef float f32x4 __attribute__((ext_vector_type(4)));
typedef unsigned short u16x4 __attribute__((ext_vector_type(4)));

#define MFMA16 __builtin_amdgcn_mfma_f32_16x16x32_bf16
#define GLOAD16(g, l) __builtin_amdgcn_global_load_lds( \
    (const __attribute__((address_space(1))) void*)(const void*)(g), \
    (__attribute__((address_space(3))) void*)(l), 16, 0, 0)

__device__ __forceinline__ u16 f2bf(float f) {
  unsigned u = __float_as_uint(f);
  return (u16)((u + 0x7FFFu + ((u >> 16) & 1u)) >> 16);
}

// XCD-aware swizzle: all gx tiles of a row-panel (and gy/8 consecutive panels)
// land on one XCD (dispatch round-robins linear id % 8). Requires gy % 8 == 0.
__device__ __forceinline__ void xcd_swizzle(int gx, int gy, int& bx, int& by) {
  int l = blockIdx.y * gx + blockIdx.x;
  int c = l & 7, j = l >> 3;
  by = c * (gy >> 3) + j / gx;
  bx = j % gx;
}

// ---------------------------------------------------------------------------
// f32 -> bf16 convert (n % 4 == 0)
// ---------------------------------------------------------------------------
__global__ __launch_bounds__(256) void cvt_bf16(const float* __restrict__ in,
                                                u16* __restrict__ out, int n) {
  int i = (blockIdx.x * 256 + threadIdx.x) * 4;
  if (i >= n) return;
  float4 v = *(const float4*)&in[i];
  u16x4 o; o[0] = f2bf(v.x); o[1] = f2bf(v.y); o[2] = f2bf(v.z); o[3] = f2bf(v.w);
  *(u16x4*)&out[i] = o;
}

// ---------------------------------------------------------------------------
// f32 [R][C] -> bf16 [R][C] (pitch out_p) AND bf16 transposed [C][R] (pitch outT_p)
// grid (C/64, R/64)
// ---------------------------------------------------------------------------
__global__ __launch_bounds__(256) void cvt_tr(const float* __restrict__ in,
                                              u16* __restrict__ out, u16* __restrict__ outT,
                                              int C, int out_p, int outT_p) {
  __shared__ u16 T[64][72];
  const int t = threadIdx.x;
  const int r0 = blockIdx.y * 64, c0 = blockIdx.x * 64;
  const int r = t >> 3, c8 = (t & 7) * 8;
#pragma unroll
  for (int p = 0; p < 2; p++) {
    const float* ip = &in[(size_t)(r0 + r + p * 32) * C + c0 + c8];
    float4 v0 = *(const float4*)ip, v1 = *(const float4*)(ip + 4);
    u16 tmp[8] = {f2bf(v0.x), f2bf(v0.y), f2bf(v0.z), f2bf(v0.w),
                  f2bf(v1.x), f2bf(v1.y), f2bf(v1.z), f2bf(v1.w)};
    *(uint4*)&out[(size_t)(r0 + r + p * 32) * out_p + c0 + c8] = *(uint4*)tmp;
    *(uint4*)&T[r + p * 32][c8] = *(uint4*)tmp;
  }
  __syncthreads();
#pragma unroll
  for (int p = 0; p < 2; p++) {
    int oc = r + p * 32;
    u16 tmp[8];
#pragma unroll
    for (int j = 0; j < 8; j++) tmp[j] = T[c8 + j][oc];
    *(uint4*)&outT[(size_t)(c0 + oc) * outT_p + r0 + c8] = *(uint4*)tmp;
  }
}

// ---------------------------------------------------------------------------
// Batched 64x64-tiled bf16 transpose. base = ptr + (z/inner)*bs_o + (z%inner)*bs_i
// ---------------------------------------------------------------------------
__global__ __launch_bounds__(256) void transpose_bf16(
    const u16* __restrict__ in, u16* __restrict__ out,
    int in_pitch, int out_pitch, int inner_n,
    long in_bs_o, long in_bs_i, long out_bs_o, long out_bs_i) {
  __shared__ u16 T[64][72];
  const int t = threadIdx.x;
  const int bz = blockIdx.z;
  const long iboff = (long)(bz / inner_n) * in_bs_o + (long)(bz % inner_n) * in_bs_i;
  const long oboff = (long)(bz / inner_n) * out_bs_o + (long)(bz % inner_n) * out_bs_i;
  const u16* ip = in + iboff + (long)(blockIdx.y * 64) * in_pitch + blockIdx.x * 64;
  u16* op = out + oboff + (long)(blockIdx.x * 64) * out_pitch + blockIdx.y * 64;
  const int r = t >> 3, c8 = (t & 7) * 8;
#pragma unroll
  for (int p = 0; p < 2; p++)
    *(uint4*)&T[r + p * 32][c8] = *(const uint4*)(ip + (size_t)(r + p * 32) * in_pitch + c8);
  __syncthreads();
#pragma unroll
  for (int p = 0; p < 2; p++) {
    int oc = r + p * 32;
    u16 tmp[8];
#pragma unroll
    for (int j = 0; j < 8; j++) tmp[j] = T[c8 + j][oc];
    *(uint4*)(op + (size_t)oc * out_pitch + c8) = *(uint4*)tmp;
  }
}

// ---------------------------------------------------------------------------
// bf16 MFMA GEMM: C[M,N] = A[M,K] * B[N,K]^T, bf16 out. 128x128 tile, BK=32.
// A staged in LDS (global_load_lds); B-fragments loaded DIRECTLY from global
// into registers with one-step prefetch (B is L2-resident weight data).
// XCD-swizzled. grid (N/128, M/128), gy % 8 == 0.
// ---------------------------------------------------------------------------
template<bool RELU>
__global__ __launch_bounds__(256) void gemm_bf16(
    const u16* __restrict__ A, const u16* __restrict__ B, u16* __restrict__ C,
    int M, int N, int K) {
  __shared__ u16 As[128 * 32];
  int bx, by;
  xcd_swizzle(gridDim.x, gridDim.y, bx, by);
  const int t = threadIdx.x, l = t & 63, w = t >> 6;
  const int lq = l & 15, quad = l >> 4;
  const int bm = by * 128, bn = bx * 128;
  const int wm = (w & 1) * 64, wn = (w >> 1) * 64;
  f32x4 acc[4][4];
#pragma unroll
  for (int i = 0; i < 4; i++)
#pragma unroll
    for (int j = 0; j < 4; j++) acc[i][j] = (f32x4){0.f, 0.f, 0.f, 0.f};

  const u16* Bp[4];
#pragma unroll
  for (int nt = 0; nt < 4; nt++)
    Bp[nt] = B + (size_t)(bn + wn + nt * 16 + lq) * K + quad * 8;
  s16x8 bf_cur[4], bf_nxt[4];
#pragma unroll
  for (int nt = 0; nt < 4; nt++) bf_cur[nt] = *(const s16x8*)Bp[nt];

  for (int k0 = 0; k0 < K; k0 += 32) {
#pragma unroll
    for (int p = 0; p < 2; p++) {
      int idx = p * 256 + t;
      GLOAD16(A + (size_t)(bm + (idx >> 2)) * K + k0 + (idx & 3) * 8, As + idx * 8);
    }
    const bool more = (k0 + 32) < K;
    if (more) {
#pragma unroll
      for (int nt = 0; nt < 4; nt++) bf_nxt[nt] = *(const s16x8*)(Bp[nt] + k0 + 32);
    }
    __syncthreads();
    s16x8 af[4];
#pragma unroll
    for (int mt = 0; mt < 4; mt++) af[mt] = *(const s16x8*)&As[(wm + mt * 16 + lq) * 32 + quad * 8];
#pragma unroll
    for (int mt = 0; mt < 4; mt++)
#pragma unroll
      for (int nt = 0; nt < 4; nt++)
        acc[mt][nt] = MFMA16(af[mt], bf_cur[nt], acc[mt][nt], 0, 0, 0);
    if (more) {
#pragma unroll
      for (int nt = 0; nt < 4; nt++) bf_cur[nt] = bf_nxt[nt];
    }
    __syncthreads();
  }
#pragma unroll
  for (int mt = 0; mt < 4; mt++)
#pragma unroll
    for (int nt = 0; nt < 4; nt++) {
      int row = bm + wm + mt * 16 + quad * 4;
      int col = bn + wn + nt * 16 + lq;
#pragma unroll
      for (int r = 0; r < 4; r++) {
        float v = acc[mt][nt][r];
        if (RELU) v = fmaxf(v, 0.f);
        C[(size_t)(row + r) * N + col] = f2bf(v);
      }
    }
}

// ---------------------------------------------------------------------------
// Fused output GEMM (no atomics): each block owns a 128x64 tile of
// out[8192][768], accumulating BOTH sources in-register:
//   out = AV12[8192][1536] @ WqkT^T + hid[8192][3072] @ WmT^T
// A via LDS; B (weights, 4KB/step block-wide) direct-from-global w/ prefetch.
// grid (12, 64) = 768 blocks, XCD-swizzled.
// ---------------------------------------------------------------------------
__global__ __launch_bounds__(256) void gemm_out2(
    const u16* __restrict__ AV12, const u16* __restrict__ hid,
    const u16* __restrict__ WqkT, const u16* __restrict__ WmT,
    float* __restrict__ out) {
  __shared__ u16 As[128 * 32];
  int bx, by;
  xcd_swizzle(gridDim.x, gridDim.y, bx, by);
  const int t = threadIdx.x, l = t & 63, w = t >> 6;
  const int lq = l & 15, quad = l >> 4;
  const int bm = by * 128, bn = bx * 64;
  const int wm = w * 32;
  f32x4 acc[2][4];
#pragma unroll
  for (int i = 0; i < 2; i++)
#pragma unroll
    for (int j = 0; j < 4; j++) acc[i][j] = (f32x4){0.f, 0.f, 0.f, 0.f};

#pragma unroll
  for (int src = 0; src < 2; src++) {
    const u16* A = src ? hid : AV12;
    const u16* B = src ? WmT : WqkT;
    const int pitch = src ? HIDq : QKP;
    const int Kend = src ? HIDq : QKP;
    const u16* Bp[4];
#pragma unroll
    for (int nt = 0; nt < 4; nt++)
      Bp[nt] = B + (size_t)(bn + nt * 16 + lq) * pitch + quad * 8;
    s16x8 bf_cur[4], bf_nxt[4];
#pragma unroll
    for (int nt = 0; nt < 4; nt++) bf_cur[nt] = *(const s16x8*)Bp[nt];

    for (int k0 = 0; k0 < Kend; k0 += 32) {
#pragma unroll
      for (int p = 0; p < 2; p++) {
        int idx = p * 256 + t;
        GLOAD16(A + (size_t)(bm + (idx >> 2)) * pitch + k0 + (idx & 3) * 8, As + idx * 8);
      }
      const bool more = (k0 + 32) < Kend;
      if (more) {
#pragma unroll
        for (int nt = 0; nt < 4; nt++) bf_nxt[nt] = *(const s16x8*)(Bp[nt] + k0 + 32);
      }
      __syncthreads();
      s16x8 af[2];
#pragma unroll
      for (int mt = 0; mt < 2; mt++)
        af[mt] = *(const s16x8*)&As[(wm + mt * 16 + lq) * 32 + quad * 8];
#pragma unroll
      for (int mt = 0; mt < 2; mt++)
#pragma unroll
        for (int nt = 0; nt < 4; nt++)
          acc[mt][nt] = MFMA16(af[mt], bf_cur[nt], acc[mt][nt], 0, 0, 0);
      if (more) {
#pragma unroll
        for (int nt = 0; nt < 4; nt++) bf_cur[nt] = bf_nxt[nt];
      }
      __syncthreads();
    }
  }
#pragma unroll
  for (int mt = 0; mt < 2; mt++)
#pragma unroll
    for (int nt = 0; nt < 4; nt++) {
      int row = bm + wm + mt * 16 + quad * 4;
      int col = bn + nt * 16 + lq;
#pragma unroll
      for (int r = 0; r < 4; r++)
        out[(size_t)(row + r) * Dq + col] = acc[mt][nt][r];
    }
}

// ---------------------------------------------------------------------------
// Attention pass 1 (no max pass; scores are O(1), exp-safe): per (b,h,64-q).
// P = exp(beta*S), l = sum_k, AV1 = (P/l) @ K via MFMA. Writes AV12[:,0:768], l.
// Q B-fragments hoisted (kt-invariant). XCD-swizzled: 12 bh-panels per XCD.
// ---------------------------------------------------------------------------
__global__ __launch_bounds__(256) void attn_pass1(
    const u16* __restrict__ QKb, const u16* __restrict__ KbT,
    const float* __restrict__ betas, u16* __restrict__ AV12,
    float* __restrict__ lg) {
  __shared__ u16 Qs[2][64][32];
  __shared__ u16 Ks[2][64][32];
  __shared__ u16 Kts[2][64][32];
  __shared__ u16 Ps[64][72];
  __shared__ float red[4][64];
  __shared__ float li[64];

  const int t = threadIdx.x, l = t & 63, w = t >> 6;
  const int lq = l & 15, quad = l >> 4;
  const int c = blockIdx.x & 7, j = blockIdx.x >> 3;
  const int bh = c * 12 + j / 16, qt = j % 16;
  const int b = bh / Hq, h = bh % Hq;
  const int q0 = qt * 64;
  const float beta = betas[h];
  const u16* Qh = QKb + (size_t)(b * Nq) * QKP + h * 64;
  const u16* Kh = Qh + Dq;
  const u16* KTh = KbT + (size_t)bh * 64 * Nq;
  u16* QsF = &Qs[0][0][0]; u16* KsF = &Ks[0][0][0]; u16* KtsF = &Kts[0][0][0];

#pragma unroll
  for (int p = 0; p < 2; p++) {
    int idx = p * 256 + t;
    GLOAD16(Qh + (size_t)(q0 + ((idx >> 2) & 63)) * QKP + (idx >> 8) * 32 + (idx & 3) * 8,
            QsF + idx * 8);
  }
  __syncthreads();
  s16x8 bqf[2][4];
#pragma unroll
  for (int zs = 0; zs < 2; zs++)
#pragma unroll
    for (int nt = 0; nt < 4; nt++)
      bqf[zs][nt] = *(const s16x8*)&Qs[zs][nt * 16 + lq][quad * 8];

  float lsum[4] = {0.f, 0.f, 0.f, 0.f};
  f32x4 ao[4];
#pragma unroll
  for (int nt = 0; nt < 4; nt++) ao[nt] = (f32x4){0.f, 0.f, 0.f, 0.f};

  for (int kt = 0; kt < 16; kt++) {
#pragma unroll
    for (int p = 0; p < 2; p++) {
      int idx = p * 256 + t;
      GLOAD16(Kh + (size_t)(kt * 64 + ((idx >> 2) & 63)) * QKP + (idx >> 8) * 32 + (idx & 3) * 8,
              KsF + idx * 8);
      GLOAD16(KTh + (size_t)((idx >> 2) & 63) * Nq + kt * 64 + (idx >> 8) * 32 + (idx & 3) * 8,
              KtsF + idx * 8);
    }
    __syncthreads();
    // S^T tile: col q = nt*16+lq, row k = kt*64 + w*16 + quad*4 + r
    f32x4 sc[4];
#pragma unroll
    for (int nt = 0; nt < 4; nt++) sc[nt] = (f32x4){0.f, 0.f, 0.f, 0.f};
#pragma unroll
    for (int zs = 0; zs < 2; zs++) {
      s16x8 a = *(const s16x8*)&Ks[zs][w * 16 + lq][quad * 8];
#pragma unroll
      for (int nt = 0; nt < 4; nt++)
        sc[nt] = MFMA16(a, bqf[zs][nt], sc[nt], 0, 0, 0);
    }
#pragma unroll
    for (int nt = 0; nt < 4; nt++) {
      u16x4 pk;
#pragma unroll
      for (int r = 0; r < 4; r++) {
        float e = __expf(sc[nt][r] * beta);
        lsum[nt] += e;
        pk[r] = f2bf(e);
      }
      *(u16x4*)&Ps[nt * 16 + lq][w * 16 + quad * 4] = pk;
    }
    __syncthreads();
    // O[q][z] += P[q][k] * K[k][z]; B-frag reads Kt rows (z-major)
#pragma unroll
    for (int ks = 0; ks < 2; ks++) {
      s16x8 a = *(const s16x8*)&Ps[w * 16 + lq][ks * 32 + quad * 8];
#pragma unroll
      for (int nt = 0; nt < 4; nt++) {
        s16x8 bk = *(const s16x8*)&Kts[ks][nt * 16 + lq][quad * 8];
        ao[nt] = MFMA16(a, bk, ao[nt], 0, 0, 0);
      }
    }
    __syncthreads();
  }
#pragma unroll
  for (int nt = 0; nt < 4; nt++) {
    float v = lsum[nt];
    v += __shfl_xor(v, 16, 64);
    v += __shfl_xor(v, 32, 64);
    if (l < 16) red[w][nt * 16 + lq] = v;
  }
  __syncthreads();
  if (t < 64) {
    float s = red[0][t] + red[1][t] + red[2][t] + red[3][t];
    lg[(size_t)bh * Nq + q0 + t] = s;
    li[t] = 1.0f / s;
  }
  __syncthreads();
  u16* Oh = AV12 + (size_t)(b * Nq + q0) * QKP + h * 64;
  float lr[4];
#pragma unroll
  for (int r = 0; r < 4; r++) lr[r] = li[w * 16 + quad * 4 + r];
#pragma unroll
  for (int nt = 0; nt < 4; nt++)
#pragma unroll
    for (int r = 0; r < 4; r++)
      Oh[(size_t)(w * 16 + quad * 4 + r) * QKP + nt * 16 + lq] = f2bf(ao[nt][r] * lr[r]);
}

// ---------------------------------------------------------------------------
// Attention pass 2: per (b,h,64-k). Recompute P from l (m=0), accumulate
// AV2[k,z] = sum_q P[q,k] Q[q,z]. K B-fragments hoisted. XCD-swizzled.
// ---------------------------------------------------------------------------
__global__ __launch_bounds__(256) void attn_pass2(
    const u16* __restrict__ QKb, const u16* __restrict__ QbT,
    const float* __restrict__ betas, u16* __restrict__ AV12,
    const float* __restrict__ lg) {
  __shared__ u16 Qs[2][64][32];
  __shared__ u16 Qts[2][64][32];
  __shared__ u16 Ks[2][64][32];
  __shared__ u16 Pts[64][72];
  __shared__ float li_s[64];

  const int t = threadIdx.x, l = t & 63, w = t >> 6;
  const int lq = l & 15, quad = l >> 4;
  const int c = blockIdx.x & 7, j = blockIdx.x >> 3;
  const int bh = c * 12 + j / 16, kt = j % 16;
  const int b = bh / Hq, h = bh % Hq;
  const int k0 = kt * 64;
  const float beta = betas[h];
  const u16* Qh = QKb + (size_t)(b * Nq) * QKP + h * 64;
  const u16* Kh = Qh + Dq;
  const u16* QTh = QbT + (size_t)bh * 64 * Nq;
  u16* QsF = &Qs[0][0][0]; u16* QtsF = &Qts[0][0][0]; u16* KsF = &Ks[0][0][0];

#pragma unroll
  for (int p = 0; p < 2; p++) {
    int idx = p * 256 + t;
    GLOAD16(Kh + (size_t)(k0 + ((idx >> 2) & 63)) * QKP + (idx >> 8) * 32 + (idx & 3) * 8,
            KsF + idx * 8);
  }
  __syncthreads();
  s16x8 bkf[2][4];
#pragma unroll
  for (int zs = 0; zs < 2; zs++)
#pragma unroll
    for (int nt = 0; nt < 4; nt++)
      bkf[zs][nt] = *(const s16x8*)&Ks[zs][nt * 16 + lq][quad * 8];

  f32x4 ao[4];
#pragma unroll
  for (int nt = 0; nt < 4; nt++) ao[nt] = (f32x4){0.f, 0.f, 0.f, 0.f};

  for (int qt = 0; qt < 16; qt++) {
#pragma unroll
    for (int p = 0; p < 2; p++) {
      int idx = p * 256 + t;
      GLOAD16(Qh + (size_t)(qt * 64 + ((idx >> 2) & 63)) * QKP + (idx >> 8) * 32 + (idx & 3) * 8,
              QsF + idx * 8);
      GLOAD16(QTh + (size_t)((idx >> 2) & 63) * Nq + qt * 64 + (idx >> 8) * 32 + (idx & 3) * 8,
              QtsF + idx * 8);
    }
    if (t < 64) li_s[t] = 1.0f / lg[(size_t)bh * Nq + qt * 64 + t];
    __syncthreads();
    f32x4 sc[4];
#pragma unroll
    for (int nt = 0; nt < 4; nt++) sc[nt] = (f32x4){0.f, 0.f, 0.f, 0.f};
#pragma unroll
    for (int zs = 0; zs < 2; zs++) {
      s16x8 a = *(const s16x8*)&Qs[zs][w * 16 + lq][quad * 8];
#pragma unroll
      for (int nt = 0; nt < 4; nt++)
        sc[nt] = MFMA16(a, bkf[zs][nt], sc[nt], 0, 0, 0);
    }
    float lr[4];
#pragma unroll
    for (int r = 0; r < 4; r++) lr[r] = li_s[w * 16 + quad * 4 + r];
#pragma unroll
    for (int nt = 0; nt < 4; nt++) {
      u16x4 pk;
#pragma unroll
      for (int r = 0; r < 4; r++)
        pk[r] = f2bf(__expf(sc[nt][r] * beta) * lr[r]);
      *(u16x4*)&Pts[nt * 16 + lq][w * 16 + quad * 4] = pk;
    }
    __syncthreads();
#pragma unroll
    for (int qs = 0; qs < 2; qs++) {
      s16x8 a = *(const s16x8*)&Pts[w * 16 + lq][qs * 32 + quad * 8];
#pragma unroll
      for (int nt = 0; nt < 4; nt++) {
        s16x8 bq = *(const s16x8*)&Qts[qs][nt * 16 + lq][quad * 8];
        ao[nt] = MFMA16(a, bq, ao[nt], 0, 0, 0);
      }
    }
    __syncthreads();
  }
  u16* Oh = AV12 + (size_t)(b * Nq + k0) * QKP + Dq + h * 64;
#pragma unroll
  for (int nt = 0; nt < 4; nt++)
#pragma unroll
    for (int r = 0; r < 4; r++)
      Oh[(size_t)(w * 16 + quad * 4 + r) * QKP + nt * 16 + lq] = f2bf(ao[nt][r]);
}

// ---------------------------------------------------------------------------
extern "C" void kernel_launch(void* const* d_in, const int* in_sizes, int n_in,
                              void* d_out, int out_size, void* d_ws, size_t ws_size,
                              hipStream_t stream) {
  const float* x     = (const float*)d_in[0];
  const float* Wq    = (const float*)d_in[1];
  const float* Wk    = (const float*)d_in[2];
  const float* betas = (const float*)d_in[3];
  const float* Wm    = (const float*)d_in[4];
  float* out = (float*)d_out;

  // workspace layout (u16 units); ~93.4 MiB
  u16* xb   = (u16*)d_ws;                      // 6,291,456
  u16* Wqkb = xb + (size_t)BN * Dq;            // 1,179,648  [1536][768]
  u16* Wmb  = Wqkb + (size_t)QKP * Dq;         // 2,359,296  [3072][768]
  u16* WqkT = Wmb + (size_t)HIDq * Dq;         // 1,179,648  [768][1536]
  u16* QKb  = WqkT + (size_t)Dq * QKP;         // 12,582,912 [8192][1536]
  u16* QbT  = QKb + (size_t)BN * QKP;          // 6,291,456  [96][64][1024]
  u16* KbT  = QbT + (size_t)Bq * Hq * Zq * Nq; // 6,291,456
  u16* AV12 = KbT + (size_t)Bq * Hq * Zq * Nq; // 12,582,912 [8192][1536]
  float* lg = (float*)(AV12 + (size_t)BN * QKP);
  u16* hidb = QKb;   // overlays QKb/QbT/KbT (dead after attention)
  u16* WmT  = xb;    // overlays xb (dead after MLP1), [768][3072]

  dim3 blk(256);
  cvt_bf16<<<(BN * Dq) / 1024, blk, 0, stream>>>(x, xb, BN * Dq);
  cvt_tr<<<dim3(12, 12), blk, 0, stream>>>(Wq, Wqkb, WqkT, Dq, Dq, QKP);
  cvt_tr<<<dim3(12, 12), blk, 0, stream>>>(Wk, Wqkb + (size_t)Dq * Dq, WqkT + Dq, Dq, Dq, QKP);
  cvt_bf16<<<(HIDq * Dq) / 1024, blk, 0, stream>>>(Wm, Wmb, HIDq * Dq);

  // QK = x @ [Wq;Wk]^T  -> bf16 [8192][1536]
  gemm_bf16<false><<<dim3(QKP / 128, BN / 128), blk, 0, stream>>>(
      xb, Wqkb, QKb, BN, QKP, Dq);

  // per-head transposes of Q and K
  transpose_bf16<<<dim3(1, 16, 96), blk, 0, stream>>>(QKb, QbT, QKP, Nq, Hq,
      (long)Nq * QKP, 64, (long)Hq * 64 * Nq, (long)64 * Nq);
  transpose_bf16<<<dim3(1, 16, 96), blk, 0, stream>>>(QKb + Dq, KbT, QKP, Nq, Hq,
      (long)Nq * QKP, 64, (long)Hq * 64 * Nq, (long)64 * Nq);

  // attention
  attn_pass1<<<Bq * Hq * 16, blk, 0, stream>>>(QKb, KbT, betas, AV12, lg);
  attn_pass2<<<Bq * Hq * 16, blk, 0, stream>>>(QKb, QbT, betas, AV12, lg);

  // MLP up-proj: hid = relu(x @ Wm^T) bf16 (overlays QKb/QbT/KbT)
  gemm_bf16<true><<<dim3(HIDq / 128, BN / 128), blk, 0, stream>>>(
      xb, Wmb, hidb, BN, HIDq, Dq);

  // Wm transpose into xb region (xb dead after MLP1)
  transpose_bf16<<<dim3(12, 48, 1), blk, 0, stream>>>(Wmb, WmT, Dq, HIDq, 1, 0, 0, 0, 0);

  // out = AV12 @ WqkT^T + hid @ WmT^T, single dispatch, no atomics
  gemm_out2<<<dim3(Dq / 64, BN / 128), blk, 0, stream>>>(AV12, hidb, WqkT, WmT, out);
}

// Round 8
// 364.849 us; speedup vs baseline: 1.8197x; 1.6051x over previous
//
#include <hip/hip_runtime.h>
#include <hip/hip_bf16.h>

#define Bq 8
#define Nq 1024
#define Dq 768
#define Hq 12
#define Zq 64
#define HIDq 3072
#define BN (Bq*Nq)            // 8192
#define QKP 1536              // pitch of fused QK / AV12 buffers

typedef unsigned short u16;
typedef short s16x8 __attribute__((ext_vector_type(8)));
typedef float f32x4 __attribute__((ext_vector_type(4)));
typedef unsigned short u16x4 __attribute__((ext_vector_type(4)));

#define MFMA16 __builtin_amdgcn_mfma_f32_16x16x32_bf16
#define GLOAD16(g, l) __builtin_amdgcn_global_load_lds( \
    (const __attribute__((address_space(1))) void*)(const void*)(g), \
    (__attribute__((address_space(3))) void*)(l), 16, 0, 0)

__device__ __forceinline__ u16 f2bf(float f) {
  unsigned u = __float_as_uint(f);
  return (u16)((u + 0x7FFFu + ((u >> 16) & 1u)) >> 16);
}

// XCD-aware swizzle: all gx tiles of a row-panel (and gy/8 consecutive panels)
// land on one XCD (dispatch round-robins linear id % 8). Requires gy % 8 == 0.
__device__ __forceinline__ void xcd_swizzle(int gx, int gy, int& bx, int& by) {
  int l = blockIdx.y * gx + blockIdx.x;
  int c = l & 7, j = l >> 3;
  by = c * (gy >> 3) + j / gx;
  bx = j % gx;
}

// ---------------------------------------------------------------------------
// f32 -> bf16 convert (n % 4 == 0)
// ---------------------------------------------------------------------------
__global__ __launch_bounds__(256) void cvt_bf16(const float* __restrict__ in,
                                                u16* __restrict__ out, int n) {
  int i = (blockIdx.x * 256 + threadIdx.x) * 4;
  if (i >= n) return;
  float4 v = *(const float4*)&in[i];
  u16x4 o; o[0] = f2bf(v.x); o[1] = f2bf(v.y); o[2] = f2bf(v.z); o[3] = f2bf(v.w);
  *(u16x4*)&out[i] = o;
}

// ---------------------------------------------------------------------------
// f32 [R][C] -> bf16 [R][C] (pitch out_p) AND bf16 transposed [C][R] (pitch outT_p)
// grid (C/64, R/64)
// ---------------------------------------------------------------------------
__global__ __launch_bounds__(256) void cvt_tr(const float* __restrict__ in,
                                              u16* __restrict__ out, u16* __restrict__ outT,
                                              int C, int out_p, int outT_p) {
  __shared__ u16 T[64][72];
  const int t = threadIdx.x;
  const int r0 = blockIdx.y * 64, c0 = blockIdx.x * 64;
  const int r = t >> 3, c8 = (t & 7) * 8;
#pragma unroll
  for (int p = 0; p < 2; p++) {
    const float* ip = &in[(size_t)(r0 + r + p * 32) * C + c0 + c8];
    float4 v0 = *(const float4*)ip, v1 = *(const float4*)(ip + 4);
    u16 tmp[8] = {f2bf(v0.x), f2bf(v0.y), f2bf(v0.z), f2bf(v0.w),
                  f2bf(v1.x), f2bf(v1.y), f2bf(v1.z), f2bf(v1.w)};
    *(uint4*)&out[(size_t)(r0 + r + p * 32) * out_p + c0 + c8] = *(uint4*)tmp;
    *(uint4*)&T[r + p * 32][c8] = *(uint4*)tmp;
  }
  __syncthreads();
#pragma unroll
  for (int p = 0; p < 2; p++) {
    int oc = r + p * 32;
    u16 tmp[8];
#pragma unroll
    for (int j = 0; j < 8; j++) tmp[j] = T[c8 + j][oc];
    *(uint4*)&outT[(size_t)(c0 + oc) * outT_p + r0 + c8] = *(uint4*)tmp;
  }
}

// ---------------------------------------------------------------------------
// Batched 64x64-tiled bf16 transpose. base = ptr + (z/inner)*bs_o + (z%inner)*bs_i
// ---------------------------------------------------------------------------
__global__ __launch_bounds__(256) void transpose_bf16(
    const u16* __restrict__ in, u16* __restrict__ out,
    int in_pitch, int out_pitch, int inner_n,
    long in_bs_o, long in_bs_i, long out_bs_o, long out_bs_i) {
  __shared__ u16 T[64][72];
  const int t = threadIdx.x;
  const int bz = blockIdx.z;
  const long iboff = (long)(bz / inner_n) * in_bs_o + (long)(bz % inner_n) * in_bs_i;
  const long oboff = (long)(bz / inner_n) * out_bs_o + (long)(bz % inner_n) * out_bs_i;
  const u16* ip = in + iboff + (long)(blockIdx.y * 64) * in_pitch + blockIdx.x * 64;
  u16* op = out + oboff + (long)(blockIdx.x * 64) * out_pitch + blockIdx.y * 64;
  const int r = t >> 3, c8 = (t & 7) * 8;
#pragma unroll
  for (int p = 0; p < 2; p++)
    *(uint4*)&T[r + p * 32][c8] = *(const uint4*)(ip + (size_t)(r + p * 32) * in_pitch + c8);
  __syncthreads();
#pragma unroll
  for (int p = 0; p < 2; p++) {
    int oc = r + p * 32;
    u16 tmp[8];
#pragma unroll
    for (int j = 0; j < 8; j++) tmp[j] = T[c8 + j][oc];
    *(uint4*)(op + (size_t)oc * out_pitch + c8) = *(uint4*)tmp;
  }
}

// ---------------------------------------------------------------------------
// bf16 MFMA GEMM: C[M,N] = A[M,K] * B[N,K]^T, bf16 out. 128x128 tile, BK=32,
// DOUBLE-BUFFERED single-barrier pipeline: stage tile k+1 after the barrier,
// before computing tile k, so load latency overlaps compute.
// XCD-swizzled. grid (N/128, M/128), gy % 8 == 0. LDS 32 KB -> 5 blocks/CU.
// ---------------------------------------------------------------------------
template<bool RELU>
__global__ __launch_bounds__(256) void gemm_bf16(
    const u16* __restrict__ A, const u16* __restrict__ B, u16* __restrict__ C,
    int M, int N, int K) {
  __shared__ u16 As[2][128 * 32];
  __shared__ u16 Bs[2][128 * 32];
  int bx, by;
  xcd_swizzle(gridDim.x, gridDim.y, bx, by);
  const int t = threadIdx.x, l = t & 63, w = t >> 6;
  const int lq = l & 15, quad = l >> 4;
  const int bm = by * 128, bn = bx * 128;
  const int wm = (w & 1) * 64, wn = (w >> 1) * 64;
  f32x4 acc[4][4];
#pragma unroll
  for (int i = 0; i < 4; i++)
#pragma unroll
    for (int j = 0; j < 4; j++) acc[i][j] = (f32x4){0.f, 0.f, 0.f, 0.f};

  auto stage = [&](int k0, int bufi) {
#pragma unroll
    for (int p = 0; p < 2; p++) {
      int idx = p * 256 + t;
      GLOAD16(A + (size_t)(bm + (idx >> 2)) * K + k0 + (idx & 3) * 8, &As[bufi][idx * 8]);
      GLOAD16(B + (size_t)(bn + (idx >> 2)) * K + k0 + (idx & 3) * 8, &Bs[bufi][idx * 8]);
    }
  };
  stage(0, 0);
  const int nIter = K >> 5;
  for (int it = 0; it < nIter; it++) {
    __syncthreads();                       // buf (it&1) ready; prior reads done
    if (it + 1 < nIter) stage((it + 1) * 32, (it + 1) & 1);   // overlaps compute
    const int bi = it & 1;
    s16x8 af[4], bf[4];
#pragma unroll
    for (int mt = 0; mt < 4; mt++)
      af[mt] = *(const s16x8*)&As[bi][(wm + mt * 16 + lq) * 32 + quad * 8];
#pragma unroll
    for (int nt = 0; nt < 4; nt++)
      bf[nt] = *(const s16x8*)&Bs[bi][(wn + nt * 16 + lq) * 32 + quad * 8];
#pragma unroll
    for (int mt = 0; mt < 4; mt++)
#pragma unroll
      for (int nt = 0; nt < 4; nt++)
        acc[mt][nt] = MFMA16(af[mt], bf[nt], acc[mt][nt], 0, 0, 0);
  }
#pragma unroll
  for (int mt = 0; mt < 4; mt++)
#pragma unroll
    for (int nt = 0; nt < 4; nt++) {
      int row = bm + wm + mt * 16 + quad * 4;
      int col = bn + wn + nt * 16 + lq;
#pragma unroll
      for (int r = 0; r < 4; r++) {
        float v = acc[mt][nt][r];
        if (RELU) v = fmaxf(v, 0.f);
        C[(size_t)(row + r) * N + col] = f2bf(v);
      }
    }
}

// ---------------------------------------------------------------------------
// Fused output GEMM (no atomics): each block owns a 128x64 tile of
// out[8192][768], accumulating BOTH sources in-register:
//   out = AV12[8192][1536] @ WqkT^T + hid[8192][3072] @ WmT^T
// BK=64 (72 tiles total), double-buffered single-barrier pipeline.
// LDS layout per buffer: As[2 ks][128][32], Bs[2 ks][64][32] (GLOAD-linear,
// read stride identical to BK=32 case). LDS 48 KB -> 3 blocks/CU = grid.
// grid (12, 64) = 768 blocks, XCD-swizzled.
// ---------------------------------------------------------------------------
__global__ __launch_bounds__(256) void gemm_out2(
    const u16* __restrict__ AV12, const u16* __restrict__ hid,
    const u16* __restrict__ WqkT, const u16* __restrict__ WmT,
    float* __restrict__ out) {
  __shared__ u16 As[2][128 * 64];   // 32 KB
  __shared__ u16 Bs[2][64 * 64];    // 16 KB
  int bx, by;
  xcd_swizzle(gridDim.x, gridDim.y, bx, by);
  const int t = threadIdx.x, l = t & 63, w = t >> 6;
  const int lq = l & 15, quad = l >> 4;
  const int bm = by * 128, bn = bx * 64;
  const int wm = w * 32;
  f32x4 acc[2][4];
#pragma unroll
  for (int i = 0; i < 2; i++)
#pragma unroll
    for (int j = 0; j < 4; j++) acc[i][j] = (f32x4){0.f, 0.f, 0.f, 0.f};

  // tiles 0..23 = AV12/WqkT (K=1536), 24..71 = hid/WmT (K=3072)
  auto stage = [&](int tl, int bufi) {
    const u16* A; const u16* B; int pitch, k0;
    if (tl < 24) { A = AV12; B = WqkT; pitch = QKP;  k0 = tl * 64; }
    else         { A = hid;  B = WmT;  pitch = HIDq; k0 = (tl - 24) * 64; }
#pragma unroll
    for (int p = 0; p < 4; p++) {
      int idx = p * 256 + t, ks = idx >> 9, rem = idx & 511;
      GLOAD16(A + (size_t)(bm + (rem >> 2)) * pitch + k0 + ks * 32 + (rem & 3) * 8,
              &As[bufi][idx * 8]);
    }
#pragma unroll
    for (int p = 0; p < 2; p++) {
      int idx = p * 256 + t, ks = idx >> 8, rem = idx & 255;
      GLOAD16(B + (size_t)(bn + (rem >> 2)) * pitch + k0 + ks * 32 + (rem & 3) * 8,
              &Bs[bufi][idx * 8]);
    }
  };
  stage(0, 0);
  for (int tl = 0; tl < 72; tl++) {
    __syncthreads();
    if (tl + 1 < 72) stage(tl + 1, (tl + 1) & 1);
    const int bi = tl & 1;
#pragma unroll
    for (int ks = 0; ks < 2; ks++) {
      s16x8 af[2], bf[4];
#pragma unroll
      for (int mt = 0; mt < 2; mt++)
        af[mt] = *(const s16x8*)&As[bi][ks * 4096 + (wm + mt * 16 + lq) * 32 + quad * 8];
#pragma unroll
      for (int nt = 0; nt < 4; nt++)
        bf[nt] = *(const s16x8*)&Bs[bi][ks * 2048 + (nt * 16 + lq) * 32 + quad * 8];
#pragma unroll
      for (int mt = 0; mt < 2; mt++)
#pragma unroll
        for (int nt = 0; nt < 4; nt++)
          acc[mt][nt] = MFMA16(af[mt], bf[nt], acc[mt][nt], 0, 0, 0);
    }
  }
#pragma unroll
  for (int mt = 0; mt < 2; mt++)
#pragma unroll
    for (int nt = 0; nt < 4; nt++) {
      int row = bm + wm + mt * 16 + quad * 4;
      int col = bn + nt * 16 + lq;
#pragma unroll
      for (int r = 0; r < 4; r++)
        out[(size_t)(row + r) * Dq + col] = acc[mt][nt][r];
    }
}

// ---------------------------------------------------------------------------
// Attention pass 1 (no max pass; scores are O(1), exp-safe): per (b,h,64-q).
// P = exp(beta*S), l = sum_k, AV1 = (P/l) @ K via MFMA. Writes AV12[:,0:768], l.
// Q B-fragments hoisted (kt-invariant). XCD-swizzled: 12 bh-panels per XCD.
// ---------------------------------------------------------------------------
__global__ __launch_bounds__(256) void attn_pass1(
    const u16* __restrict__ QKb, const u16* __restrict__ KbT,
    const float* __restrict__ betas, u16* __restrict__ AV12,
    float* __restrict__ lg) {
  __shared__ u16 Qs[2][64][32];
  __shared__ u16 Ks[2][64][32];
  __shared__ u16 Kts[2][64][32];
  __shared__ u16 Ps[64][72];
  __shared__ float red[4][64];
  __shared__ float li[64];

  const int t = threadIdx.x, l = t & 63, w = t >> 6;
  const int lq = l & 15, quad = l >> 4;
  const int c = blockIdx.x & 7, j = blockIdx.x >> 3;
  const int bh = c * 12 + j / 16, qt = j % 16;
  const int b = bh / Hq, h = bh % Hq;
  const int q0 = qt * 64;
  const float beta = betas[h];
  const u16* Qh = QKb + (size_t)(b * Nq) * QKP + h * 64;
  const u16* Kh = Qh + Dq;
  const u16* KTh = KbT + (size_t)bh * 64 * Nq;
  u16* QsF = &Qs[0][0][0]; u16* KsF = &Ks[0][0][0]; u16* KtsF = &Kts[0][0][0];

#pragma unroll
  for (int p = 0; p < 2; p++) {
    int idx = p * 256 + t;
    GLOAD16(Qh + (size_t)(q0 + ((idx >> 2) & 63)) * QKP + (idx >> 8) * 32 + (idx & 3) * 8,
            QsF + idx * 8);
  }
  __syncthreads();
  s16x8 bqf[2][4];
#pragma unroll
  for (int zs = 0; zs < 2; zs++)
#pragma unroll
    for (int nt = 0; nt < 4; nt++)
      bqf[zs][nt] = *(const s16x8*)&Qs[zs][nt * 16 + lq][quad * 8];

  float lsum[4] = {0.f, 0.f, 0.f, 0.f};
  f32x4 ao[4];
#pragma unroll
  for (int nt = 0; nt < 4; nt++) ao[nt] = (f32x4){0.f, 0.f, 0.f, 0.f};

  for (int kt = 0; kt < 16; kt++) {
#pragma unroll
    for (int p = 0; p < 2; p++) {
      int idx = p * 256 + t;
      GLOAD16(Kh + (size_t)(kt * 64 + ((idx >> 2) & 63)) * QKP + (idx >> 8) * 32 + (idx & 3) * 8,
              KsF + idx * 8);
      GLOAD16(KTh + (size_t)((idx >> 2) & 63) * Nq + kt * 64 + (idx >> 8) * 32 + (idx & 3) * 8,
              KtsF + idx * 8);
    }
    __syncthreads();
    // S^T tile: col q = nt*16+lq, row k = kt*64 + w*16 + quad*4 + r
    f32x4 sc[4];
#pragma unroll
    for (int nt = 0; nt < 4; nt++) sc[nt] = (f32x4){0.f, 0.f, 0.f, 0.f};
#pragma unroll
    for (int zs = 0; zs < 2; zs++) {
      s16x8 a = *(const s16x8*)&Ks[zs][w * 16 + lq][quad * 8];
#pragma unroll
      for (int nt = 0; nt < 4; nt++)
        sc[nt] = MFMA16(a, bqf[zs][nt], sc[nt], 0, 0, 0);
    }
#pragma unroll
    for (int nt = 0; nt < 4; nt++) {
      u16x4 pk;
#pragma unroll
      for (int r = 0; r < 4; r++) {
        float e = __expf(sc[nt][r] * beta);
        lsum[nt] += e;
        pk[r] = f2bf(e);
      }
      *(u16x4*)&Ps[nt * 16 + lq][w * 16 + quad * 4] = pk;
    }
    __syncthreads();
    // O[q][z] += P[q][k] * K[k][z]; B-frag reads Kt rows (z-major)
#pragma unroll
    for (int ks = 0; ks < 2; ks++) {
      s16x8 a = *(const s16x8*)&Ps[w * 16 + lq][ks * 32 + quad * 8];
#pragma unroll
      for (int nt = 0; nt < 4; nt++) {
        s16x8 bk = *(const s16x8*)&Kts[ks][nt * 16 + lq][quad * 8];
        ao[nt] = MFMA16(a, bk, ao[nt], 0, 0, 0);
      }
    }
    __syncthreads();
  }
#pragma unroll
  for (int nt = 0; nt < 4; nt++) {
    float v = lsum[nt];
    v += __shfl_xor(v, 16, 64);
    v += __shfl_xor(v, 32, 64);
    if (l < 16) red[w][nt * 16 + lq] = v;
  }
  __syncthreads();
  if (t < 64) {
    float s = red[0][t] + red[1][t] + red[2][t] + red[3][t];
    lg[(size_t)bh * Nq + q0 + t] = s;
    li[t] = 1.0f / s;
  }
  __syncthreads();
  u16* Oh = AV12 + (size_t)(b * Nq + q0) * QKP + h * 64;
  float lr[4];
#pragma unroll
  for (int r = 0; r < 4; r++) lr[r] = li[w * 16 + quad * 4 + r];
#pragma unroll
  for (int nt = 0; nt < 4; nt++)
#pragma unroll
    for (int r = 0; r < 4; r++)
      Oh[(size_t)(w * 16 + quad * 4 + r) * QKP + nt * 16 + lq] = f2bf(ao[nt][r] * lr[r]);
}

// ---------------------------------------------------------------------------
// Attention pass 2: per (b,h,64-k). Recompute P from l (m=0), accumulate
// AV2[k,z] = sum_q P[q,k] Q[q,z]. K B-fragments hoisted. XCD-swizzled.
// ---------------------------------------------------------------------------
__global__ __launch_bounds__(256) void attn_pass2(
    const u16* __restrict__ QKb, const u16* __restrict__ QbT,
    const float* __restrict__ betas, u16* __restrict__ AV12,
    const float* __restrict__ lg) {
  __shared__ u16 Qs[2][64][32];
  __shared__ u16 Qts[2][64][32];
  __shared__ u16 Ks[2][64][32];
  __shared__ u16 Pts[64][72];
  __shared__ float li_s[64];

  const int t = threadIdx.x, l = t & 63, w = t >> 6;
  const int lq = l & 15, quad = l >> 4;
  const int c = blockIdx.x & 7, j = blockIdx.x >> 3;
  const int bh = c * 12 + j / 16, kt = j % 16;
  const int b = bh / Hq, h = bh % Hq;
  const int k0 = kt * 64;
  const float beta = betas[h];
  const u16* Qh = QKb + (size_t)(b * Nq) * QKP + h * 64;
  const u16* Kh = Qh + Dq;
  const u16* QTh = QbT + (size_t)bh * 64 * Nq;
  u16* QsF = &Qs[0][0][0]; u16* QtsF = &Qts[0][0][0]; u16* KsF = &Ks[0][0][0];

#pragma unroll
  for (int p = 0; p < 2; p++) {
    int idx = p * 256 + t;
    GLOAD16(Kh + (size_t)(k0 + ((idx >> 2) & 63)) * QKP + (idx >> 8) * 32 + (idx & 3) * 8,
            KsF + idx * 8);
  }
  __syncthreads();
  s16x8 bkf[2][4];
#pragma unroll
  for (int zs = 0; zs < 2; zs++)
#pragma unroll
    for (int nt = 0; nt < 4; nt++)
      bkf[zs][nt] = *(const s16x8*)&Ks[zs][nt * 16 + lq][quad * 8];

  f32x4 ao[4];
#pragma unroll
  for (int nt = 0; nt < 4; nt++) ao[nt] = (f32x4){0.f, 0.f, 0.f, 0.f};

  for (int qt = 0; qt < 16; qt++) {
#pragma unroll
    for (int p = 0; p < 2; p++) {
      int idx = p * 256 + t;
      GLOAD16(Qh + (size_t)(qt * 64 + ((idx >> 2) & 63)) * QKP + (idx >> 8) * 32 + (idx & 3) * 8,
              QsF + idx * 8);
      GLOAD16(QTh + (size_t)((idx >> 2) & 63) * Nq + qt * 64 + (idx >> 8) * 32 + (idx & 3) * 8,
              QtsF + idx * 8);
    }
    if (t < 64) li_s[t] = 1.0f / lg[(size_t)bh * Nq + qt * 64 + t];
    __syncthreads();
    f32x4 sc[4];
#pragma unroll
    for (int nt = 0; nt < 4; nt++) sc[nt] = (f32x4){0.f, 0.f, 0.f, 0.f};
#pragma unroll
    for (int zs = 0; zs < 2; zs++) {
      s16x8 a = *(const s16x8*)&Qs[zs][w * 16 + lq][quad * 8];
#pragma unroll
      for (int nt = 0; nt < 4; nt++)
        sc[nt] = MFMA16(a, bkf[zs][nt], sc[nt], 0, 0, 0);
    }
    float lr[4];
#pragma unroll
    for (int r = 0; r < 4; r++) lr[r] = li_s[w * 16 + quad * 4 + r];
#pragma unroll
    for (int nt = 0; nt < 4; nt++) {
      u16x4 pk;
#pragma unroll
      for (int r = 0; r < 4; r++)
        pk[r] = f2bf(__expf(sc[nt][r] * beta) * lr[r]);
      *(u16x4*)&Pts[nt * 16 + lq][w * 16 + quad * 4] = pk;
    }
    __syncthreads();
#pragma unroll
    for (int qs = 0; qs < 2; qs++) {
      s16x8 a = *(const s16x8*)&Pts[w * 16 + lq][qs * 32 + quad * 8];
#pragma unroll
      for (int nt = 0; nt < 4; nt++) {
        s16x8 bq = *(const s16x8*)&Qts[qs][nt * 16 + lq][quad * 8];
        ao[nt] = MFMA16(a, bq, ao[nt], 0, 0, 0);
      }
    }
    __syncthreads();
  }
  u16* Oh = AV12 + (size_t)(b * Nq + k0) * QKP + Dq + h * 64;
#pragma unroll
  for (int nt = 0; nt < 4; nt++)
#pragma unroll
    for (int r = 0; r < 4; r++)
      Oh[(size_t)(w * 16 + quad * 4 + r) * QKP + nt * 16 + lq] = f2bf(ao[nt][r]);
}

// ---------------------------------------------------------------------------
extern "C" void kernel_launch(void* const* d_in, const int* in_sizes, int n_in,
                              void* d_out, int out_size, void* d_ws, size_t ws_size,
                              hipStream_t stream) {
  const float* x     = (const float*)d_in[0];
  const float* Wq    = (const float*)d_in[1];
  const float* Wk    = (const float*)d_in[2];
  const float* betas = (const float*)d_in[3];
  const float* Wm    = (const float*)d_in[4];
  float* out = (float*)d_out;

  // workspace layout (u16 units); ~93.4 MiB
  u16* xb   = (u16*)d_ws;                      // 6,291,456
  u16* Wqkb = xb + (size_t)BN * Dq;            // 1,179,648  [1536][768]
  u16* Wmb  = Wqkb + (size_t)QKP * Dq;         // 2,359,296  [3072][768]
  u16* WqkT = Wmb + (size_t)HIDq * Dq;         // 1,179,648  [768][1536]
  u16* QKb  = WqkT + (size_t)Dq * QKP;         // 12,582,912 [8192][1536]
  u16* QbT  = QKb + (size_t)BN * QKP;          // 6,291,456  [96][64][1024]
  u16* KbT  = QbT + (size_t)Bq * Hq * Zq * Nq; // 6,291,456
  u16* AV12 = KbT + (size_t)Bq * Hq * Zq * Nq; // 12,582,912 [8192][1536]
  float* lg = (float*)(AV12 + (size_t)BN * QKP);
  u16* hidb = QKb;   // overlays QKb/QbT/KbT (dead after attention)
  u16* WmT  = xb;    // overlays xb (dead after MLP1), [768][3072]

  dim3 blk(256);
  cvt_bf16<<<(BN * Dq) / 1024, blk, 0, stream>>>(x, xb, BN * Dq);
  cvt_tr<<<dim3(12, 12), blk, 0, stream>>>(Wq, Wqkb, WqkT, Dq, Dq, QKP);
  cvt_tr<<<dim3(12, 12), blk, 0, stream>>>(Wk, Wqkb + (size_t)Dq * Dq, WqkT + Dq, Dq, Dq, QKP);
  cvt_bf16<<<(HIDq * Dq) / 1024, blk, 0, stream>>>(Wm, Wmb, HIDq * Dq);

  // QK = x @ [Wq;Wk]^T  -> bf16 [8192][1536]
  gemm_bf16<false><<<dim3(QKP / 128, BN / 128), blk, 0, stream>>>(
      xb, Wqkb, QKb, BN, QKP, Dq);

  // per-head transposes of Q and K
  transpose_bf16<<<dim3(1, 16, 96), blk, 0, stream>>>(QKb, QbT, QKP, Nq, Hq,
      (long)Nq * QKP, 64, (long)Hq * 64 * Nq, (long)64 * Nq);
  transpose_bf16<<<dim3(1, 16, 96), blk, 0, stream>>>(QKb + Dq, KbT, QKP, Nq, Hq,
      (long)Nq * QKP, 64, (long)Hq * 64 * Nq, (long)64 * Nq);

  // attention
  attn_pass1<<<Bq * Hq * 16, blk, 0, stream>>>(QKb, KbT, betas, AV12, lg);
  attn_pass2<<<Bq * Hq * 16, blk, 0, stream>>>(QKb, QbT, betas, AV12, lg);

  // MLP up-proj: hid = relu(x @ Wm^T) bf16 (overlays QKb/QbT/KbT)
  gemm_bf16<true><<<dim3(HIDq / 128, BN / 128), blk, 0, stream>>>(
      xb, Wmb, hidb, BN, HIDq, Dq);

  // Wm transpose into xb region (xb dead after MLP1)
  transpose_bf16<<<dim3(12, 48, 1), blk, 0, stream>>>(Wmb, WmT, Dq, HIDq, 1, 0, 0, 0, 0);

  // out = AV12 @ WqkT^T + hid @ WmT^T, single dispatch, no atomics
  gemm_out2<<<dim3(Dq / 64, BN / 128), blk, 0, stream>>>(AV12, hidb, WqkT, WmT, out);
}